// Round 1
// baseline (353.851 us; speedup 1.0000x reference)
//
#include <hip/hip_runtime.h>

// BoundaryChunker — MI355X (gfx950)
// Strategy: skip the reference's full-length cumsum pooling; compute pooled
// vectors ONLY at boundary positions, then a f32 SIMT GEMM (no fp32 MFMA on
// CDNA4). Pipeline: memset(out) -> detect mask dtype -> pack/scan -> pool ->
// GEMM. All on `stream`, graph-capture safe.

#define B_ 8
#define L_ 4096
#define D_ 1024
#define POOLW 5
#define EPS_ 1e-6f

// ---------------------------------------------------------------- detect ----
// The harness marshalling of a JAX bool array is ambiguous (u8 / i32 / f32).
// Read the first B_*L_ bytes (valid under every candidate encoding) and
// classify by byte-position pattern:
//   i32: nonzero bytes only at pos%4==0 (little-endian value 1)
//   f32: 1.0f = [00 00 80 3F] -> nonzero only at pos%4 in {2,3}
//   u8 : nonzero bytes at all residues
__global__ void detect_kernel(const unsigned char* __restrict__ mask,
                              int* __restrict__ flag) {
    __shared__ int c_lo_s, c_hi_s;
    if (threadIdx.x == 0) { c_lo_s = 0; c_hi_s = 0; }
    __syncthreads();
    int c_lo = 0, c_hi = 0;
    const int n = B_ * L_;
    for (int i = threadIdx.x; i < n; i += blockDim.x) {
        unsigned char v = mask[i];
        if (v) { if ((i & 3) == 0) c_lo++; else c_hi++; }
    }
    atomicAdd(&c_lo_s, c_lo);
    atomicAdd(&c_hi_s, c_hi);
    __syncthreads();
    if (threadIdx.x == 0) {
        int f;
        if (c_hi_s == 0)      f = 1;  // int32
        else if (c_lo_s == 0) f = 2;  // float32
        else                  f = 0;  // bytes (bool/u8)
        *flag = f;
    }
}

__device__ __forceinline__ int mask_val(const void* mask, int flag, int i) {
    if (flag == 0) return ((const unsigned char*)mask)[i] != 0;
    if (flag == 1) return ((const int*)mask)[i] != 0;
    return ((const float*)mask)[i] != 0.0f;
}

// ------------------------------------------------------------------ pack ----
// One block (256 threads) per batch row. Block-scan of mask counts; boundary
// position t gets slot u = exclusive_prefix. Emits t_idx (ws) and the
// slot_mask / idx / conf outputs directly. Inactive slots stay memset-zero.
__global__ __launch_bounds__(256) void pack_kernel(
    const void* __restrict__ mask, const float* __restrict__ conf_in,
    const int* __restrict__ flag_p, int* __restrict__ counts,
    int* __restrict__ t_idx, float* __restrict__ out_mask,
    float* __restrict__ out_idx, float* __restrict__ out_conf, int U) {
    const int b   = blockIdx.x;
    const int tid = threadIdx.x;
    const int flag = *flag_p;
    __shared__ int scan[256];
    const int base = b * L_;
    int vals[16];
    int cnt = 0;
#pragma unroll
    for (int j = 0; j < 16; ++j) {
        int t = tid * 16 + j;
        int v = mask_val(mask, flag, base + t);
        vals[j] = v;
        cnt += v;
    }
    scan[tid] = cnt;
    __syncthreads();
    for (int off = 1; off < 256; off <<= 1) {
        int v   = scan[tid];
        int add = (tid >= off) ? scan[tid - off] : 0;
        __syncthreads();
        scan[tid] = v + add;
        __syncthreads();
    }
    const int excl = scan[tid] - cnt;
    if (tid == 0) counts[b] = scan[255];
    int u = excl;
#pragma unroll
    for (int j = 0; j < 16; ++j) {
        if (vals[j]) {
            int t = tid * 16 + j;
            t_idx[b * U + u]    = t;
            out_mask[b * U + u] = 1.0f;
            out_idx[b * U + u]  = (float)t;
            out_conf[b * U + u] = conf_in[base + t];
            ++u;
        }
    }
}

// ------------------------------------------------------------------ pool ----
// One block per (b,u) slot: pooled[d] = sum_{s=start..t} cs[s]*emb[b,s,d]
//                                       / (sum cs + EPS)
__global__ __launch_bounds__(256) void pool_kernel(
    const float* __restrict__ emb, const float* __restrict__ cs,
    const int* __restrict__ counts, const int* __restrict__ t_idx,
    float* __restrict__ pooled, int U) {
    const int m = blockIdx.x;  // b*U + u
    const int b = m / U, u = m % U;
    if (u >= counts[b]) return;
    const int t     = t_idx[m];
    const int start = (t - POOLW + 1) > 0 ? (t - POOLW + 1) : 0;
    float wsum = 0.f;
    for (int s = start; s <= t; ++s) wsum += cs[b * L_ + s];
    const float inv = 1.0f / (wsum + EPS_);
    const int d0 = threadIdx.x * 4;
    float4 acc = make_float4(0.f, 0.f, 0.f, 0.f);
    for (int s = start; s <= t; ++s) {
        const float w  = cs[b * L_ + s];
        const float4 e = *(const float4*)&emb[((long)b * L_ + s) * D_ + d0];
        acc.x += w * e.x; acc.y += w * e.y; acc.z += w * e.z; acc.w += w * e.w;
    }
    float4 r = make_float4(acc.x * inv, acc.y * inv, acc.z * inv, acc.w * inv);
    *(float4*)&pooled[(long)m * D_ + d0] = r;
}

// ------------------------------------------------------------------ gemm ----
// C[m,n] = sum_k P[m,k] * W[n,k] + bias[n], only for active slots.
// f32 SIMT GEMM: 64x64 tile, BK=32, 256 threads, 4x4 micro-tile/thread.
#define BM 64
#define BN 64
#define BK 32

__global__ __launch_bounds__(256) void gemm_kernel(
    const float* __restrict__ P, const float* __restrict__ W,
    const float* __restrict__ bias, const int* __restrict__ counts,
    float* __restrict__ C, int M, int U) {
    __shared__ float Ps[BK][BM + 4];  // pad: row stride 272B (16B-aligned)
    __shared__ float Ws[BK][BN + 4];
    const int bm  = blockIdx.x * BM;
    const int bn  = blockIdx.y * BN;
    const int tid = threadIdx.x;
    const int tx = tid & 15, ty = tid >> 4;
    float acc[4][4] = {};
    const int lr = tid >> 3;        // 0..31
    const int lc = (tid & 7) * 4;   // 0,4,..,28

    for (int k0 = 0; k0 < D_; k0 += BK) {
#pragma unroll
        for (int h = 0; h < 2; ++h) {
            const int r  = lr + h * 32;
            const int gm = bm + r;
            float4 a = make_float4(0.f, 0.f, 0.f, 0.f);
            if (gm < M) a = *(const float4*)&P[(long)gm * D_ + k0 + lc];
            Ps[lc + 0][r] = a.x; Ps[lc + 1][r] = a.y;
            Ps[lc + 2][r] = a.z; Ps[lc + 3][r] = a.w;
            const float4 w4 = *(const float4*)&W[(long)(bn + r) * D_ + k0 + lc];
            Ws[lc + 0][r] = w4.x; Ws[lc + 1][r] = w4.y;
            Ws[lc + 2][r] = w4.z; Ws[lc + 3][r] = w4.w;
        }
        __syncthreads();
#pragma unroll
        for (int kk = 0; kk < BK; ++kk) {
            const float4 a4 = *(const float4*)&Ps[kk][ty * 4];
            const float4 b4 = *(const float4*)&Ws[kk][tx * 4];
            const float a[4]  = {a4.x, a4.y, a4.z, a4.w};
            const float bb[4] = {b4.x, b4.y, b4.z, b4.w};
#pragma unroll
            for (int i = 0; i < 4; ++i)
#pragma unroll
                for (int j = 0; j < 4; ++j) acc[i][j] += a[i] * bb[j];
        }
        __syncthreads();
    }
#pragma unroll
    for (int i = 0; i < 4; ++i) {
        const int m = bm + ty * 4 + i;
        if (m >= M) continue;
        const int b_ = m / U, u = m % U;
        if (u >= counts[b_]) continue;
#pragma unroll
        for (int j = 0; j < 4; ++j) {
            const int n = bn + tx * 4 + j;
            C[(long)m * D_ + n] = acc[i][j] + bias[n];
        }
    }
}

// ---------------------------------------------------------------- launch ----
extern "C" void kernel_launch(void* const* d_in, const int* in_sizes, int n_in,
                              void* d_out, int out_size, void* d_ws,
                              size_t ws_size, hipStream_t stream) {
    const float* emb     = (const float*)d_in[0];
    const void*  mask    = d_in[1];
    const float* cs      = (const float*)d_in[2];
    const float* conf_in = (const float*)d_in[3];
    const float* W       = (const float*)d_in[4];
    const float* bias    = (const float*)d_in[5];

    // out_size = B*U*(D+3)  ->  recover U (max_units fixed at trace time)
    const int U = out_size / (B_ * (D_ + 3));
    const int M = B_ * U;

    float* out_chunks = (float*)d_out;                  // (B,U,D)
    float* out_mask   = out_chunks + (size_t)M * D_;    // (B,U)
    float* out_idx    = out_mask + M;                   // (B,U)
    float* out_conf   = out_idx + M;                    // (B,U)

    // workspace layout
    char* ws = (char*)d_ws;
    int* flag   = (int*)ws;                 // 4 B
    int* counts = (int*)(ws + 64);          // B_ ints
    int* t_idx  = (int*)(ws + 128);         // M ints
    size_t pooled_off = (128 + (size_t)M * 4 + 255) & ~(size_t)255;
    float* pooled = (float*)(ws + pooled_off);  // M * D_ floats

    // zero all outputs (inactive slots must be exactly 0)
    hipMemsetAsync(d_out, 0, (size_t)out_size * sizeof(float), stream);

    detect_kernel<<<1, 256, 0, stream>>>((const unsigned char*)mask, flag);
    pack_kernel<<<B_, 256, 0, stream>>>(mask, conf_in, flag, counts, t_idx,
                                        out_mask, out_idx, out_conf, U);
    pool_kernel<<<M, 256, 0, stream>>>(emb, cs, counts, t_idx, pooled, U);
    dim3 ggrid((M + BM - 1) / BM, D_ / BN);
    gemm_kernel<<<ggrid, 256, 0, stream>>>(pooled, W, bias, counts, out_chunks,
                                           M, U);
}

// Round 2
// 290.970 us; speedup vs baseline: 1.2161x; 1.2161x over previous
//
#include <hip/hip_runtime.h>

// BoundaryChunker — MI355X (gfx950), round 2
// Pipeline: pack(+fused dtype detect, zero-fill) -> wconv (W f32->bf16 hi/lo)
//           -> pool (boundary slots only, emits bf16 hi/lo) -> MFMA GEMM.
// GEMM uses split-bf16: C = Phi*Whi + Phi*Wlo + Plo*Whi (error ~2^-17 rel),
// fragments loaded straight from global (L2/L3-resident), no LDS.

#define B_ 8
#define L_ 4096
#define D_ 1024
#define POOLW 5
#define EPS_ 1e-6f

typedef __attribute__((ext_vector_type(8))) short bf16x8;
typedef __attribute__((ext_vector_type(4))) float f32x4;

__device__ __forceinline__ unsigned short bf16_rne(float v) {
    unsigned u = __float_as_uint(v);
    unsigned r = u + 0x7FFFu + ((u >> 16) & 1u);
    return (unsigned short)(r >> 16);
}
__device__ __forceinline__ float bf16_f32(unsigned short h) {
    return __uint_as_float(((unsigned)h) << 16);
}

__device__ __forceinline__ int mask_val(const void* mask, int flag, int i) {
    if (flag == 0) return ((const unsigned char*)mask)[i] != 0;
    if (flag == 1) return ((const int*)mask)[i] != 0;
    return ((const float*)mask)[i] != 0.0f;
}

// ------------------------------------------------------------------ pack ----
// One block per batch row. Fused mask-dtype detection (each block reads its
// own 4KB slice of the raw bytes — valid prefix under every encoding, and any
// 4KB slice contains >=~64 nonzero entries at p=1/16), zero-fills the
// mask/idx/conf output slots, then block-scans the mask and scatters.
__global__ __launch_bounds__(256) void pack_kernel(
    const void* __restrict__ mask, const float* __restrict__ conf_in,
    int* __restrict__ counts, int* __restrict__ t_idx,
    float* __restrict__ out_mask, float* __restrict__ out_idx,
    float* __restrict__ out_conf, int U) {
    const int b   = blockIdx.x;
    const int tid = threadIdx.x;
    __shared__ int s_clo, s_chi, s_flag;
    __shared__ int scan[256];
    if (tid == 0) { s_clo = 0; s_chi = 0; }
    __syncthreads();
    // --- detect: classify by byte-residue pattern of nonzero bytes ---
    // i32(1)=0x00000001 -> only low byte; f32(1.0)=0x3F800000 -> only high
    // bytes; u8 -> both.
    const uint4 wv = ((const uint4*)mask)[b * 256 + tid];
    const unsigned wd[4] = {wv.x, wv.y, wv.z, wv.w};
    int clo = 0, chi = 0;
#pragma unroll
    for (int i = 0; i < 4; ++i) {
        clo += ((wd[i] & 0x000000FFu) != 0u);
        chi += ((wd[i] & 0xFFFFFF00u) != 0u);
    }
    if (clo) atomicAdd(&s_clo, clo);
    if (chi) atomicAdd(&s_chi, chi);
    // --- zero-fill output slots (d_out is poisoned before every call) ---
    for (int u = tid; u < U; u += 256) {
        out_mask[b * U + u] = 0.0f;
        out_idx[b * U + u]  = 0.0f;
        out_conf[b * U + u] = 0.0f;
    }
    __syncthreads();
    if (tid == 0) s_flag = (s_chi == 0) ? 1 : ((s_clo == 0) ? 2 : 0);
    __syncthreads();
    const int flag = s_flag;
    // --- scan + scatter ---
    const int base = b * L_;
    int vals[16];
    int cnt = 0;
#pragma unroll
    for (int j = 0; j < 16; ++j) {
        int v = mask_val(mask, flag, base + tid * 16 + j);
        vals[j] = v;
        cnt += v;
    }
    scan[tid] = cnt;
    __syncthreads();
    for (int off = 1; off < 256; off <<= 1) {
        int v   = scan[tid];
        int add = (tid >= off) ? scan[tid - off] : 0;
        __syncthreads();
        scan[tid] = v + add;
        __syncthreads();
    }
    const int excl = scan[tid] - cnt;
    if (tid == 0) counts[b] = scan[255];
    int u = excl;
#pragma unroll
    for (int j = 0; j < 16; ++j) {
        if (vals[j]) {
            const int t = tid * 16 + j;
            t_idx[b * U + u]    = t;
            out_mask[b * U + u] = 1.0f;
            out_idx[b * U + u]  = (float)t;
            out_conf[b * U + u] = conf_in[base + t];
            ++u;
        }
    }
}

// ----------------------------------------------------------------- wconv ----
// W (1024x1024 f32, row-major [n][k]) -> Whi/Wlo bf16 (RNE hi + residual lo).
__global__ __launch_bounds__(256) void wconv_kernel(
    const float* __restrict__ W, unsigned short* __restrict__ Whi,
    unsigned short* __restrict__ Wlo) {
    const int i = (blockIdx.x * 256 + threadIdx.x) * 4;
    const float4 v = *(const float4*)&W[i];
    ushort4 hi, lo;
    hi.x = bf16_rne(v.x); lo.x = bf16_rne(v.x - bf16_f32(hi.x));
    hi.y = bf16_rne(v.y); lo.y = bf16_rne(v.y - bf16_f32(hi.y));
    hi.z = bf16_rne(v.z); lo.z = bf16_rne(v.z - bf16_f32(hi.z));
    hi.w = bf16_rne(v.w); lo.w = bf16_rne(v.w - bf16_f32(hi.w));
    *(ushort4*)&Whi[i] = hi;
    *(ushort4*)&Wlo[i] = lo;
}

// ------------------------------------------------------------------ pool ----
// One block per (b,u) slot; emits pooled vector as bf16 hi/lo split.
__global__ __launch_bounds__(256) void pool_kernel(
    const float* __restrict__ emb, const float* __restrict__ cs,
    const int* __restrict__ counts, const int* __restrict__ t_idx,
    unsigned short* __restrict__ Phi, unsigned short* __restrict__ Plo,
    int U) {
    const int m = blockIdx.x;  // b*U + u
    const int b = m / U, u = m - b * U;
    if (u >= counts[b]) return;
    const int t     = t_idx[m];
    const int start = (t - POOLW + 1) > 0 ? (t - POOLW + 1) : 0;
    float wsum = 0.f;
    for (int s = start; s <= t; ++s) wsum += cs[b * L_ + s];
    const float inv = 1.0f / (wsum + EPS_);
    const int d0 = threadIdx.x * 4;
    float4 acc = make_float4(0.f, 0.f, 0.f, 0.f);
    for (int s = start; s <= t; ++s) {
        const float w  = cs[b * L_ + s];
        const float4 e = *(const float4*)&emb[((size_t)(b * L_ + s)) * D_ + d0];
        acc.x += w * e.x; acc.y += w * e.y; acc.z += w * e.z; acc.w += w * e.w;
    }
    acc.x *= inv; acc.y *= inv; acc.z *= inv; acc.w *= inv;
    ushort4 hi, lo;
    hi.x = bf16_rne(acc.x); lo.x = bf16_rne(acc.x - bf16_f32(hi.x));
    hi.y = bf16_rne(acc.y); lo.y = bf16_rne(acc.y - bf16_f32(hi.y));
    hi.z = bf16_rne(acc.z); lo.z = bf16_rne(acc.z - bf16_f32(hi.z));
    hi.w = bf16_rne(acc.w); lo.w = bf16_rne(acc.w - bf16_f32(hi.w));
    *(ushort4*)&Phi[(size_t)m * D_ + d0] = hi;
    *(ushort4*)&Plo[(size_t)m * D_ + d0] = lo;
}

// ------------------------------------------------------------------ gemm ----
// C[m,n] = sum_k P[m,k]*W[n,k] + bias[n] via mfma_f32_16x16x32_bf16.
// Block = 64x64 tile, 4 waves in 2x2; wave = 32x32 (2x2 fragments).
// Fragment layouts (m89-verified): A lane l -> row l&15, k = 8*(l>>4)+j
// (8 contiguous bf16 = 16B load); B lane l -> col l&15 (= W row), same k.
// C/D lane l, reg r -> row (l>>4)*4+r, col l&15.
__global__ __launch_bounds__(256) void gemm_kernel(
    const unsigned short* __restrict__ Phi, const unsigned short* __restrict__ Plo,
    const unsigned short* __restrict__ Whi, const unsigned short* __restrict__ Wlo,
    const float* __restrict__ bias, const int* __restrict__ counts,
    float* __restrict__ C, int M, int U) {
    const int tid  = threadIdx.x;
    const int w    = tid >> 6;
    const int lane = tid & 63;
    const int bm = blockIdx.x * 64, bn = blockIdx.y * 64;
    const int wm = (w >> 1) * 32, wn = (w & 1) * 32;
    const int lr = lane & 15;
    const int lk = (lane >> 4) * 8;

    const size_t aoff0 = (size_t)(bm + wm + lr) * D_ + lk;
    const size_t aoff1 = aoff0 + (size_t)16 * D_;
    const size_t boff0 = (size_t)(bn + wn + lr) * D_ + lk;
    const size_t boff1 = boff0 + (size_t)16 * D_;

    f32x4 acc[2][2] = {};
#pragma unroll 2
    for (int k = 0; k < D_; k += 32) {
        bf16x8 ah[2], al[2], bh[2], bl[2];
        ah[0] = *(const bf16x8*)(Phi + aoff0 + k);
        ah[1] = *(const bf16x8*)(Phi + aoff1 + k);
        al[0] = *(const bf16x8*)(Plo + aoff0 + k);
        al[1] = *(const bf16x8*)(Plo + aoff1 + k);
        bh[0] = *(const bf16x8*)(Whi + boff0 + k);
        bh[1] = *(const bf16x8*)(Whi + boff1 + k);
        bl[0] = *(const bf16x8*)(Wlo + boff0 + k);
        bl[1] = *(const bf16x8*)(Wlo + boff1 + k);
#pragma unroll
        for (int i = 0; i < 2; ++i)
#pragma unroll
            for (int j = 0; j < 2; ++j) {
                acc[i][j] = __builtin_amdgcn_mfma_f32_16x16x32_bf16(
                    ah[i], bh[j], acc[i][j], 0, 0, 0);
                acc[i][j] = __builtin_amdgcn_mfma_f32_16x16x32_bf16(
                    ah[i], bl[j], acc[i][j], 0, 0, 0);
                acc[i][j] = __builtin_amdgcn_mfma_f32_16x16x32_bf16(
                    al[i], bh[j], acc[i][j], 0, 0, 0);
            }
    }
    // epilogue: bias + zero inactive slots (covers the removed memset)
#pragma unroll
    for (int i = 0; i < 2; ++i)
#pragma unroll
        for (int j = 0; j < 2; ++j) {
            const int n  = bn + wn + j * 16 + lr;
            const float bv = bias[n];
#pragma unroll
            for (int r = 0; r < 4; ++r) {
                const int m = bm + wm + i * 16 + (lane >> 4) * 4 + r;
                if (m >= M) continue;
                const int b_ = m / U;
                const int u  = m - b_ * U;
                const float val =
                    (u < counts[b_]) ? (acc[i][j][r] + bv) : 0.0f;
                C[(size_t)m * D_ + n] = val;
            }
        }
}

// ---------------------------------------------------------------- launch ----
extern "C" void kernel_launch(void* const* d_in, const int* in_sizes, int n_in,
                              void* d_out, int out_size, void* d_ws,
                              size_t ws_size, hipStream_t stream) {
    const float* emb     = (const float*)d_in[0];
    const void*  mask    = d_in[1];
    const float* cs      = (const float*)d_in[2];
    const float* conf_in = (const float*)d_in[3];
    const float* W       = (const float*)d_in[4];
    const float* bias    = (const float*)d_in[5];

    const int U    = out_size / (B_ * (D_ + 3));
    const int M    = B_ * U;
    const int Mpad = (M + 63) & ~63;

    float* out_chunks = (float*)d_out;                  // (B,U,D)
    float* out_mask   = out_chunks + (size_t)M * D_;    // (B,U)
    float* out_idx    = out_mask + M;                   // (B,U)
    float* out_conf   = out_idx + M;                    // (B,U)

    // workspace layout (16B-aligned chunks)
    char* ws = (char*)d_ws;
    int* counts = (int*)ws;                                   // 8 ints
    int* t_idx  = (int*)(ws + 256);                           // Mpad ints
    size_t off  = (256 + (size_t)Mpad * 4 + 255) & ~(size_t)255;
    unsigned short* Phi = (unsigned short*)(ws + off);        // Mpad*D bf16
    off += (size_t)Mpad * D_ * 2;
    unsigned short* Plo = (unsigned short*)(ws + off);
    off += (size_t)Mpad * D_ * 2;
    unsigned short* Whi = (unsigned short*)(ws + off);        // D*D bf16
    off += (size_t)D_ * D_ * 2;
    unsigned short* Wlo = (unsigned short*)(ws + off);

    pack_kernel<<<B_, 256, 0, stream>>>(mask, conf_in, counts, t_idx,
                                        out_mask, out_idx, out_conf, U);
    wconv_kernel<<<D_ * D_ / 1024, 256, 0, stream>>>(W, Whi, Wlo);
    pool_kernel<<<M, 256, 0, stream>>>(emb, cs, counts, t_idx, Phi, Plo, U);
    dim3 ggrid(Mpad / 64, D_ / 64);
    gemm_kernel<<<ggrid, 256, 0, stream>>>(Phi, Plo, Whi, Wlo, bias, counts,
                                           out_chunks, M, U);
}